// Round 12
// baseline (102.300 us; speedup 1.0000x reference)
//
#include <hip/hip_runtime.h>

#define CC 512
#define TT 4096
#define NB 4
#define NH 8
#define HD 64

typedef __attribute__((ext_vector_type(8))) short s16x8;
typedef __attribute__((ext_vector_type(4))) float f32x4;
typedef __attribute__((ext_vector_type(4))) unsigned int u32x4;

#if defined(__has_builtin)
#  if __has_builtin(__builtin_amdgcn_fdot2_f32_bf16)
#    define HAS_BF16_DOT2 1
#  else
#    define HAS_BF16_DOT2 0
#  endif
#else
#  define HAS_BF16_DOT2 0
#endif

// float -> bf16 bits, round-to-nearest-even
__device__ __forceinline__ short f2bf(float f) {
    unsigned u = __float_as_uint(f);
    unsigned r = (u + 0x7fffu + ((u >> 16) & 1u)) >> 16;
    return (short)r;
}
__device__ __forceinline__ float bf2f(short s) {
    return __uint_as_float(((unsigned)(unsigned short)s) << 16);
}

#if HAS_BF16_DOT2
typedef __attribute__((ext_vector_type(2))) __bf16 bf16x2;
__device__ __forceinline__ float dot2bf(unsigned a, unsigned b, float c) {
    return __builtin_amdgcn_fdot2_f32_bf16(__builtin_bit_cast(bf16x2, a),
                                           __builtin_bit_cast(bf16x2, b), c, false);
}
#else
__device__ __forceinline__ float dot2bf(unsigned a, unsigned b, float c) {
    float r = fmaf(bf2f((short)(a & 0xffffu)), bf2f((short)(b & 0xffffu)), c);
    return fmaf(bf2f((short)(a >> 16)), bf2f((short)(b >> 16)), r);
}
#endif

__device__ __forceinline__ void gld_lds16(const void* g, void* s) {
    __builtin_amdgcn_global_load_lds(
        (const __attribute__((address_space(1))) unsigned int*)g,
        (__attribute__((address_space(3))) unsigned int*)s, 16, 0, 0);
}

// ---------------- weight fp32 -> bf16 (4 matrices concatenated) ----------------
__global__ __launch_bounds__(256) void cvt_w_k(const float* __restrict__ w0,
                                               const float* __restrict__ w1,
                                               const float* __restrict__ w2,
                                               const float* __restrict__ w3,
                                               short* __restrict__ dst) {
    int i = blockIdx.x * 256 + threadIdx.x;  // 4*262144 total
    const float* s = (i < 262144) ? w0 : (i < 524288) ? w1 : (i < 786432) ? w2 : w3;
    dst[i] = f2bf(s[i & 262143]);
}

// ---------- transpose+convert: fp32 (B,C,T) -> bf16 (B,T,C), x and cond -------
// NOTE: measured at HBM roofline (100.6 MB traffic ~= 15us) — do not touch.
__global__ __launch_bounds__(256) void trans_k(const float* __restrict__ x,
                                               const float* __restrict__ cond,
                                               short* __restrict__ xT,
                                               short* __restrict__ condT) {
    __shared__ float tile[64][65];
    int z = blockIdx.z;          // 0..7
    int b = z & 3;
    const float* src = (z < 4 ? x : cond) + (size_t)b * CC * TT;
    short* dst = (z < 4 ? xT : condT) + (size_t)b * TT * CC;
    int tx = threadIdx.x & 63, ty = threadIdx.x >> 6;
    int t0 = blockIdx.x * 64, c0 = blockIdx.y * 64;
#pragma unroll
    for (int r = 0; r < 64; r += 4)
        tile[ty + r][tx] = src[(size_t)(c0 + ty + r) * TT + t0 + tx];
    __syncthreads();
#pragma unroll
    for (int r = 0; r < 64; r += 4)
        dst[(size_t)(t0 + ty + r) * CC + c0 + tx] = f2bf(tile[tx][ty + r]);
}

// ======== QKV GEMM: 256x256x64, 8 waves, quadrant-phase counted-vmcnt ========
// D[t][o] bf16 = (W*S^T)^T + bias.  S: [4096][512] (t,k); W: [512][512] (o,k).
// 8 waves: wr=wid>>2 (t), wc=wid&3 (o). Wave t-rows = mh*128+wr*64+mi*16;
// o-cols = nh*128+wc*32+ni*16. Phase order (mh,nh): (0,0)(0,1)(1,1)(1,0) —
// each phase consumes exactly one A-half (mh) and one B-half (nh) of LDS.
// Staging of kt+1 issues one half per phase (A0@p1,B0@p2,B1@p3,A1@p4), so the
// counted waits vmcnt(4) leave 4-6 loads in flight across raw s_barriers:
//   p4 wait retires A0',B0' (needed p1');  p1 wait retires B1 (needed p2);
//   p2 wait retires A1 (needed p3);  p3 no wait. kt=7: drain 2 -> 0.
__global__ __launch_bounds__(512, 2) void gemm_qkv8_k(
    const short* __restrict__ Wb, const short* __restrict__ xT,
    const short* __restrict__ condT, const float* __restrict__ bq,
    const float* __restrict__ bk, const float* __restrict__ bv,
    short* __restrict__ qkvT) {
    __shared__ short Sl[2][256 * 64] __attribute__((aligned(16)));
    __shared__ short Wl[2][256 * 64] __attribute__((aligned(16)));
    const int z = blockIdx.z, which = z >> 2, b = z & 3;
    const short* Wm = Wb + (size_t)which * CC * CC;
    const short* Sm = (which == 0 ? xT : condT) + (size_t)b * TT * CC;
    const float* bias = which == 0 ? bq : (which == 1 ? bk : bv);
    short* Db = qkvT + ((size_t)which * NB + b) * TT * CC;

    const int tid = threadIdx.x;
    const int lane = tid & 63, wid = tid >> 6;
    const int wr = wid >> 2;   // 0..1
    const int wc = wid & 3;    // 0..3
    const int t0 = blockIdx.x * 256;
    const int o0 = blockIdx.y * 256;
    const short* SA = Sm + (size_t)t0 * CC;
    const short* WA = Wm + (size_t)o0 * CC;

// stage one half-tile (128 rows x 8 chunks) of MAT into buffer BUF at k-col K0.
// LDS dest linear in idx2 (wave-uniform base + lane*16); source pre-swizzled
// chunk c = s ^ (row&7) so LDS slot s holds chunk c (proven conflict-free).
#define STAGE(MAT, SRC, HALF, BUF, K0)                                        \
    {                                                                         \
        _Pragma("unroll") for (int l = 0; l < 2; ++l) {                       \
            int idx2 = l * 512 + tid;                                         \
            int row = (HALF)*128 + (idx2 >> 3), sl_ = idx2 & 7;               \
            int c = sl_ ^ (row & 7);                                          \
            gld_lds16(SRC + (size_t)row * CC + (K0) + c * 8,                  \
                      &MAT[BUF][((HALF)*1024 + idx2) * 8]);                   \
        }                                                                     \
    }

#define READ_A(MH, BUF)                                                       \
    _Pragma("unroll") for (int kk = 0; kk < 2; ++kk)                          \
    _Pragma("unroll") for (int mi = 0; mi < 4; ++mi) {                        \
        int R = (MH)*128 + wr * 64 + mi * 16 + (lane & 15);                   \
        int g = kk * 4 + (lane >> 4);                                         \
        a[kk][mi] = *(const s16x8*)&Sl[BUF][(R * 8 + (g ^ (R & 7))) * 8];     \
    }

#define READ_B(NH, BUF)                                                       \
    _Pragma("unroll") for (int kk = 0; kk < 2; ++kk)                          \
    _Pragma("unroll") for (int ni = 0; ni < 2; ++ni) {                        \
        int R = (NH)*128 + wc * 32 + ni * 16 + (lane & 15);                   \
        int g = kk * 4 + (lane >> 4);                                         \
        bb[kk][ni] = *(const s16x8*)&Wl[BUF][(R * 8 + (g ^ (R & 7))) * 8];    \
    }

#define MFMA_Q(MH, NH)                                                        \
    __builtin_amdgcn_s_setprio(1);                                            \
    _Pragma("unroll") for (int mi = 0; mi < 4; ++mi)                          \
    _Pragma("unroll") for (int ni = 0; ni < 2; ++ni)                          \
    _Pragma("unroll") for (int kk = 0; kk < 2; ++kk)                          \
        acc[MH][mi][NH][ni] = __builtin_amdgcn_mfma_f32_16x16x32_bf16(        \
            a[kk][mi], bb[kk][ni], acc[MH][mi][NH][ni], 0, 0, 0);             \
    __builtin_amdgcn_s_setprio(0);

#define BAR()                       \
    __builtin_amdgcn_s_barrier();   \
    __builtin_amdgcn_sched_barrier(0);

    f32x4 acc[2][4][2][2];
#pragma unroll
    for (int i = 0; i < 2; i++)
#pragma unroll
        for (int j = 0; j < 4; j++)
#pragma unroll
            for (int k = 0; k < 2; k++)
#pragma unroll
                for (int l = 0; l < 2; l++) acc[i][j][k][l] = (f32x4){0.f, 0.f, 0.f, 0.f};
    s16x8 a[2][4];
    s16x8 bb[2][2];

    // prologue: stage kt=0 fully (order A0,B0,B1,A1); retire A0,B0; publish.
    STAGE(Sl, SA, 0, 0, 0);
    STAGE(Wl, WA, 0, 0, 0);
    STAGE(Wl, WA, 1, 0, 0);
    STAGE(Sl, SA, 1, 0, 0);
    asm volatile("s_waitcnt vmcnt(4)" ::: "memory");
    BAR();

    for (int kt = 0; kt < 8; ++kt) {
        const int buf = kt & 1, nbuf = buf ^ 1;
        const int kn = (kt + 1) * 64;
        // ---- p1: quadrant (mh0, nh0) ----
        if (kt < 7) {
            STAGE(Sl, SA, 0, nbuf, kn);                       // A0'
            asm volatile("s_waitcnt vmcnt(4)" ::: "memory");  // retire B1(kt)
        } else {
            asm volatile("s_waitcnt vmcnt(2)" ::: "memory");
        }
        BAR();
        READ_A(0, buf);
        READ_B(0, buf);
        MFMA_Q(0, 0);
        // ---- p2: (mh0, nh1) — A reused ----
        if (kt < 7) {
            STAGE(Wl, WA, 0, nbuf, kn);                       // B0'
            asm volatile("s_waitcnt vmcnt(4)" ::: "memory");  // retire A1(kt)
        } else {
            asm volatile("s_waitcnt vmcnt(0)" ::: "memory");
        }
        BAR();
        READ_B(1, buf);
        MFMA_Q(0, 1);
        // ---- p3: (mh1, nh1) — B reused ----
        if (kt < 7) STAGE(Wl, WA, 1, nbuf, kn);               // B1'
        BAR();
        READ_A(1, buf);
        MFMA_Q(1, 1);
        // ---- p4: (mh1, nh0) — A reused ----
        if (kt < 7) {
            STAGE(Sl, SA, 1, nbuf, kn);                       // A1'
            asm volatile("s_waitcnt vmcnt(4)" ::: "memory");  // retire A0',B0'
        }
        BAR();
        READ_B(0, buf);
        MFMA_Q(1, 0);
    }
#undef STAGE
#undef READ_A
#undef READ_B
#undef MFMA_Q
#undef BAR

    // epilogue: C/D layout col=lane&15, row=(lane>>4)*4+r
    const int col = lane & 15;
    const int rg = (lane >> 4) << 2;
#pragma unroll
    for (int mh = 0; mh < 2; ++mh)
#pragma unroll
        for (int mi = 0; mi < 4; ++mi) {
            int t = t0 + mh * 128 + wr * 64 + mi * 16 + rg;
#pragma unroll
            for (int nh = 0; nh < 2; ++nh)
#pragma unroll
                for (int ni = 0; ni < 2; ++ni) {
                    int o = o0 + nh * 128 + wc * 32 + ni * 16 + col;
                    float bv = bias[o];
                    f32x4 v = acc[mh][mi][nh][ni];
#pragma unroll
                    for (int r = 0; r < 4; r++)
                        Db[(size_t)(t + r) * CC + o] = f2bf(v[r] + bv);
                }
        }
}

// ---------------- 128x128x64 bf16 MFMA GEMM core (r5-proven, gemm_o) ---------
__device__ __forceinline__ void gemm128_o(const short* __restrict__ Wm,
                                          const short* __restrict__ Sm,
                                          const float* __restrict__ bias,
                                          float* __restrict__ Df) {
    __shared__ short Al[128 * 64] __attribute__((aligned(16)));
    __shared__ short Bl[128 * 64] __attribute__((aligned(16)));
    const int tid = threadIdx.x;
    const int lane = tid & 63;
    const int wid = tid >> 6;
    const int o0 = blockIdx.y * 128;
    const int t0 = blockIdx.x * 128;
    const int wm = (wid >> 1) * 64;
    const int wn = (wid & 1) * 64;

    f32x4 acc[4][4];
#pragma unroll
    for (int i = 0; i < 4; i++)
#pragma unroll
        for (int j = 0; j < 4; j++) acc[i][j] = (f32x4){0.f, 0.f, 0.f, 0.f};

    const int cbase = (wid * 4) << 6;

    for (int kt = 0; kt < 8; ++kt) {
        const int k0 = kt * 64;
        __syncthreads();
#pragma unroll
        for (int j = 0; j < 4; ++j) {
            int c = cbase + (j << 6) + lane;
            int m = c >> 3, kc = c & 7;
            int kcs = kc ^ (m & 7);
            gld_lds16(Wm + (size_t)(o0 + m) * CC + k0 + kcs * 8,
                      &Al[(cbase + (j << 6)) << 3]);
            gld_lds16(Sm + (size_t)(t0 + m) * CC + k0 + kcs * 8,
                      &Bl[(cbase + (j << 6)) << 3]);
        }
        __syncthreads();
#pragma unroll
        for (int kk = 0; kk < 2; ++kk) {
            const int kb = kk * 32 + (lane >> 4) * 8;
            s16x8 af[4], bfr[4];
#pragma unroll
            for (int i = 0; i < 4; i++) {
                int m = wm + i * 16 + (lane & 15);
                af[i] = *(const s16x8*)&Al[(m * 64 + kb) ^ ((m & 7) << 3)];
                int n = wn + i * 16 + (lane & 15);
                bfr[i] = *(const s16x8*)&Bl[(n * 64 + kb) ^ ((n & 7) << 3)];
            }
#pragma unroll
            for (int mi = 0; mi < 4; mi++)
#pragma unroll
                for (int ni = 0; ni < 4; ni++)
                    acc[mi][ni] = __builtin_amdgcn_mfma_f32_16x16x32_bf16(
                        af[mi], bfr[ni], acc[mi][ni], 0, 0, 0);
        }
    }

    const int col = lane & 15;
    const int rg = (lane >> 4) << 2;
#pragma unroll
    for (int mi = 0; mi < 4; mi++) {
        int o = o0 + wm + mi * 16 + rg;
#pragma unroll
        for (int ni = 0; ni < 4; ni++) {
            int t = t0 + wn + ni * 16 + col;
            f32x4 v = acc[mi][ni];
#pragma unroll
            for (int r = 0; r < 4; r++)
                Df[(size_t)(o + r) * TT + t] = v[r] + bias[o + r];
        }
    }
}

__global__ __launch_bounds__(256, 2) void gemm_o_k(const short* __restrict__ Wb,
                                                   const short* __restrict__ outT,
                                                   const float* __restrict__ bo,
                                                   float* __restrict__ out) {
    int b = blockIdx.z;
    gemm128_o(Wb + 3 * (size_t)CC * CC, outT + (size_t)b * TT * CC, bo,
              out + (size_t)b * CC * TT);
}

// ---------------- windowed attention v5 (r5-exact) ----------------
__global__ __launch_bounds__(64, 4) void attn5_k(const short* __restrict__ qkvT,
                                                 short* __restrict__ outT) {
    __shared__ unsigned kl[640 * 4] __attribute__((aligned(16)));
    __shared__ unsigned vl[640 * 4] __attribute__((aligned(16)));
    const int lane = threadIdx.x;
    const int t0 = blockIdx.x * 64;
    const int h = blockIdx.y, b = blockIdx.z;
    const size_t BTC = (size_t)NB * TT * CC;
    const short* qg = qkvT + (size_t)b * TT * CC + h * HD;
    const short* kg = qg + BTC;
    const short* vg = qg + 2 * BTC;

#pragma unroll
    for (int it = 0; it < 10; ++it) {
        int idx = it * 64 + lane;
        int row = idx >> 3, s = idx & 7;
        int c = s ^ (row & 7);
        int t = t0 - 8 + row;
        t = t < 0 ? 0 : (t > TT - 1 ? TT - 1 : t);
        const size_t off = (size_t)t * CC + c * 8;
        gld_lds16(kg + off, &kl[it * 256]);
        gld_lds16(vg + off, &vl[it * 256]);
    }

    u32x4 qv[8];
    {
        const u32x4* qr = (const u32x4*)(qg + (size_t)(t0 + lane) * CC);
#pragma unroll
        for (int c = 0; c < 8; ++c) qv[c] = qr[c];
    }

    __syncthreads();

    float dots[16];
#pragma unroll
    for (int w = 0; w < 16; ++w) {
        const int row = lane + w;
        float a0 = 0.f, a1 = 0.f, a2 = 0.f, a3 = 0.f;
#pragma unroll
        for (int c = 0; c < 8; ++c) {
            u32x4 kc = *(const u32x4*)&kl[(row * 8 + (c ^ (row & 7))) * 4];
            a0 = dot2bf(qv[c][0], kc[0], a0);
            a1 = dot2bf(qv[c][1], kc[1], a1);
            a2 = dot2bf(qv[c][2], kc[2], a2);
            a3 = dot2bf(qv[c][3], kc[3], a3);
        }
        int s = t0 - 8 + row;
        dots[w] = ((unsigned)s < (unsigned)TT) ? ((a0 + a1) + (a2 + a3)) * 0.125f
                                               : 0.f;
    }

    unsigned pp[8];
    {
        float mx = dots[0];
#pragma unroll
        for (int w = 1; w < 16; ++w) mx = fmaxf(mx, dots[w]);
        float e[16], sum = 0.f;
#pragma unroll
        for (int w = 0; w < 16; ++w) {
            e[w] = __expf(dots[w] - mx);
            sum += e[w];
        }
        const float inv = 1.f / sum;
        const int sb = t0 - 8 + lane;
#pragma unroll
        for (int i = 0; i < 8; ++i) {
            float p0 = ((unsigned)(sb + 2 * i) < (unsigned)TT) ? e[2 * i] * inv : 0.f;
            float p1 = ((unsigned)(sb + 2 * i + 1) < (unsigned)TT) ? e[2 * i + 1] * inv : 0.f;
            pp[i] = (unsigned)(unsigned short)f2bf(p0) |
                    ((unsigned)(unsigned short)f2bf(p1) << 16);
        }
    }

    short* ob = outT + ((size_t)b * TT + t0 + lane) * CC + h * HD;
#pragma unroll
    for (int half = 0; half < 2; ++half) {
        float of[32];
#pragma unroll
        for (int j = 0; j < 32; ++j) of[j] = 0.f;
#pragma unroll
        for (int i = 0; i < 8; ++i) {
            const int r0 = lane + 2 * i, r1 = r0 + 1;
#pragma unroll
            for (int cl = 0; cl < 4; ++cl) {
                const int c = half * 4 + cl;
                u32x4 va = *(const u32x4*)&vl[(r0 * 8 + (c ^ (r0 & 7))) * 4];
                u32x4 vb = *(const u32x4*)&vl[(r1 * 8 + (c ^ (r1 & 7))) * 4];
#pragma unroll
                for (int d = 0; d < 4; ++d) {
                    unsigned lo = __builtin_amdgcn_perm(vb[d], va[d], 0x05040100u);
                    unsigned hi = __builtin_amdgcn_perm(vb[d], va[d], 0x07060302u);
                    of[cl * 8 + 2 * d]     = dot2bf(pp[i], lo, of[cl * 8 + 2 * d]);
                    of[cl * 8 + 2 * d + 1] = dot2bf(pp[i], hi, of[cl * 8 + 2 * d + 1]);
                }
            }
        }
#pragma unroll
        for (int cl = 0; cl < 4; ++cl) {
            s16x8 pk;
#pragma unroll
            for (int j = 0; j < 8; ++j) pk[j] = f2bf(of[cl * 8 + j]);
            *(s16x8*)&ob[half * 32 + cl * 8] = pk;
        }
    }
}

extern "C" void kernel_launch(void* const* d_in, const int* in_sizes, int n_in,
                              void* d_out, int out_size, void* d_ws, size_t ws_size,
                              hipStream_t stream) {
    const float* x    = (const float*)d_in[0];
    const float* cond = (const float*)d_in[1];
    const float* Wq   = (const float*)d_in[2];
    const float* bq   = (const float*)d_in[3];
    const float* Wk   = (const float*)d_in[4];
    const float* bk   = (const float*)d_in[5];
    const float* Wv   = (const float*)d_in[6];
    const float* bv   = (const float*)d_in[7];
    const float* Wo   = (const float*)d_in[8];
    const float* bo   = (const float*)d_in[9];

    char* ws = (char*)d_ws;
    // layout: Wb(2MB) | xT(16MB) | condT(16MB) | qkvT bf16 (48MB)
    short* Wb    = (short*)ws;
    short* xT    = (short*)(ws + (2u << 20));
    short* condT = (short*)(ws + (18u << 20));
    short* qkvT  = (short*)(ws + (34u << 20));
    short* outT  = xT;  // xT dead after Q GEMM; reuse for attention output^T

    cvt_w_k<<<4096, 256, 0, stream>>>(Wq, Wk, Wv, Wo, Wb);
    trans_k<<<dim3(TT / 64, CC / 64, 8), 256, 0, stream>>>(x, cond, xT, condT);
    gemm_qkv8_k<<<dim3(TT / 256, CC / 256, 12), 512, 0, stream>>>(Wb, xT, condT, bq, bk, bv, qkvT);
    attn5_k<<<dim3(TT / 64, NH, NB), 64, 0, stream>>>(qkvT, outT);
    gemm_o_k<<<dim3(TT / 128, CC / 128, NB), 256, 0, stream>>>(Wb, outT, bo, (float*)d_out);
}

// Round 13
// 90.278 us; speedup vs baseline: 1.1332x; 1.1332x over previous
//
#include <hip/hip_runtime.h>

#define CC 512
#define TT 4096
#define NB 4
#define NH 8
#define HD 64

typedef __attribute__((ext_vector_type(8))) short s16x8;
typedef __attribute__((ext_vector_type(4))) float f32x4;
typedef __attribute__((ext_vector_type(4))) unsigned int u32x4;

#if defined(__has_builtin)
#  if __has_builtin(__builtin_amdgcn_fdot2_f32_bf16)
#    define HAS_BF16_DOT2 1
#  else
#    define HAS_BF16_DOT2 0
#  endif
#else
#  define HAS_BF16_DOT2 0
#endif

// float -> bf16 bits, round-to-nearest-even
__device__ __forceinline__ short f2bf(float f) {
    unsigned u = __float_as_uint(f);
    unsigned r = (u + 0x7fffu + ((u >> 16) & 1u)) >> 16;
    return (short)r;
}
__device__ __forceinline__ float bf2f(short s) {
    return __uint_as_float(((unsigned)(unsigned short)s) << 16);
}

#if HAS_BF16_DOT2
typedef __attribute__((ext_vector_type(2))) __bf16 bf16x2;
__device__ __forceinline__ float dot2bf(unsigned a, unsigned b, float c) {
    return __builtin_amdgcn_fdot2_f32_bf16(__builtin_bit_cast(bf16x2, a),
                                           __builtin_bit_cast(bf16x2, b), c, false);
}
#else
__device__ __forceinline__ float dot2bf(unsigned a, unsigned b, float c) {
    float r = fmaf(bf2f((short)(a & 0xffffu)), bf2f((short)(b & 0xffffu)), c);
    return fmaf(bf2f((short)(a >> 16)), bf2f((short)(b >> 16)), r);
}
#endif

__device__ __forceinline__ void gld_lds16(const void* g, void* s) {
    __builtin_amdgcn_global_load_lds(
        (const __attribute__((address_space(1))) unsigned int*)g,
        (__attribute__((address_space(3))) unsigned int*)s, 16, 0, 0);
}

// ---------------- weight fp32 -> bf16 (4 matrices concatenated) ----------------
__global__ __launch_bounds__(256) void cvt_w_k(const float* __restrict__ w0,
                                               const float* __restrict__ w1,
                                               const float* __restrict__ w2,
                                               const float* __restrict__ w3,
                                               short* __restrict__ dst) {
    int i = blockIdx.x * 256 + threadIdx.x;  // 4*262144 total
    const float* s = (i < 262144) ? w0 : (i < 524288) ? w1 : (i < 786432) ? w2 : w3;
    dst[i] = f2bf(s[i & 262143]);
}

// ---------- transpose+convert: fp32 (B,C,T) -> bf16 (B,T,C), x and cond -------
// NOTE: measured at HBM roofline (100.6 MB traffic ~= 15us) — do not touch.
__global__ __launch_bounds__(256) void trans_k(const float* __restrict__ x,
                                               const float* __restrict__ cond,
                                               short* __restrict__ xT,
                                               short* __restrict__ condT) {
    __shared__ float tile[64][65];
    int z = blockIdx.z;          // 0..7
    int b = z & 3;
    const float* src = (z < 4 ? x : cond) + (size_t)b * CC * TT;
    short* dst = (z < 4 ? xT : condT) + (size_t)b * TT * CC;
    int tx = threadIdx.x & 63, ty = threadIdx.x >> 6;
    int t0 = blockIdx.x * 64, c0 = blockIdx.y * 64;
#pragma unroll
    for (int r = 0; r < 64; r += 4)
        tile[ty + r][tx] = src[(size_t)(c0 + ty + r) * TT + t0 + tx];
    __syncthreads();
#pragma unroll
    for (int r = 0; r < 64; r += 4)
        dst[(size_t)(t0 + ty + r) * CC + c0 + tx] = f2bf(tile[tx][ty + r]);
}

// ---------------- 128x128x64 bf16 MFMA GEMM core (r5-proven) ----------------
// Wm: [512][512] bf16 (o,k) row-major. Sm: [4096][512] bf16 (t,k) row-major.
// TMAJOR=0: Df[o][t] fp32 = W*S^T + bias.
// TMAJOR=1: Db[t][o] bf16 = (W*S^T)^T + bias (swapped MFMA operands).
// 2-barrier-per-K-tile structure: measured structural ceiling for this shape
// (qkv ~34us ~= 758 TF); dbuf-prefetch (r8), A-from-L2 (r7), KV-fusion (r10),
// and a derived 8-phase counted-vmcnt port (r12) all measured worse.
template <int TMAJOR>
__device__ __forceinline__ void gemm128(const short* __restrict__ Wm,
                                        const short* __restrict__ Sm,
                                        const float* __restrict__ bias,
                                        float* __restrict__ Df,
                                        short* __restrict__ Db) {
    __shared__ short Al[128 * 64] __attribute__((aligned(16)));
    __shared__ short Bl[128 * 64] __attribute__((aligned(16)));
    const int tid = threadIdx.x;
    const int lane = tid & 63;
    const int wid = tid >> 6;
    const int o0 = blockIdx.y * 128;
    const int t0 = blockIdx.x * 128;
    const int wm = (wid >> 1) * 64;
    const int wn = (wid & 1) * 64;

    f32x4 acc[4][4];
#pragma unroll
    for (int i = 0; i < 4; i++)
#pragma unroll
        for (int j = 0; j < 4; j++) acc[i][j] = (f32x4){0.f, 0.f, 0.f, 0.f};

    const int cbase = (wid * 4) << 6;  // chunk base for this wave (64 chunks/call)

    for (int kt = 0; kt < 8; ++kt) {
        const int k0 = kt * 64;
        __syncthreads();  // previous tile's reads complete
#pragma unroll
        for (int j = 0; j < 4; ++j) {
            int c = cbase + (j << 6) + lane;   // 16B chunk index 0..1023
            int m = c >> 3, kc = c & 7;
            int kcs = kc ^ (m & 7);            // pre-swizzled source chunk
            gld_lds16(Wm + (size_t)(o0 + m) * CC + k0 + kcs * 8,
                      &Al[(cbase + (j << 6)) << 3]);
            gld_lds16(Sm + (size_t)(t0 + m) * CC + k0 + kcs * 8,
                      &Bl[(cbase + (j << 6)) << 3]);
        }
        __syncthreads();  // drains vmcnt(0): staged data visible
#pragma unroll
        for (int kk = 0; kk < 2; ++kk) {
            const int kb = kk * 32 + (lane >> 4) * 8;
            s16x8 af[4], bfr[4];
#pragma unroll
            for (int i = 0; i < 4; i++) {
                int m = wm + i * 16 + (lane & 15);
                af[i] = *(const s16x8*)&Al[(m * 64 + kb) ^ ((m & 7) << 3)];
                int n = wn + i * 16 + (lane & 15);
                bfr[i] = *(const s16x8*)&Bl[(n * 64 + kb) ^ ((n & 7) << 3)];
            }
#pragma unroll
            for (int mi = 0; mi < 4; mi++)
#pragma unroll
                for (int ni = 0; ni < 4; ni++) {
                    if (TMAJOR)   // rows = t (bfr tile), cols = o (af tile)
                        acc[mi][ni] = __builtin_amdgcn_mfma_f32_16x16x32_bf16(
                            bfr[mi], af[ni], acc[mi][ni], 0, 0, 0);
                    else
                        acc[mi][ni] = __builtin_amdgcn_mfma_f32_16x16x32_bf16(
                            af[mi], bfr[ni], acc[mi][ni], 0, 0, 0);
                }
        }
    }

    const int col = lane & 15;
    const int rg = (lane >> 4) << 2;
    if (TMAJOR) {
#pragma unroll
        for (int ti = 0; ti < 4; ti++) {
            int t = t0 + wn + ti * 16 + rg;
#pragma unroll
            for (int oi = 0; oi < 4; oi++) {
                int o = o0 + wm + oi * 16 + col;
                float bv = bias[o];
                f32x4 a = acc[ti][oi];
#pragma unroll
                for (int r = 0; r < 4; r++)
                    Db[(size_t)(t + r) * CC + o] = f2bf(a[r] + bv);
            }
        }
    } else {
#pragma unroll
        for (int mi = 0; mi < 4; mi++) {
            int o = o0 + wm + mi * 16 + rg;
#pragma unroll
            for (int ni = 0; ni < 4; ni++) {
                int t = t0 + wn + ni * 16 + col;
                f32x4 a = acc[mi][ni];
#pragma unroll
                for (int r = 0; r < 4; r++)
                    Df[(size_t)(o + r) * TT + t] = a[r] + bias[o + r];
            }
        }
    }
}

// QKV: writes bf16 [which][b][t][C]
__global__ __launch_bounds__(256, 2) void gemm_qkv_k(
    const short* __restrict__ Wb, const short* __restrict__ xT,
    const short* __restrict__ condT, const float* __restrict__ bq,
    const float* __restrict__ bk, const float* __restrict__ bv,
    short* __restrict__ qkvT) {
    int z = blockIdx.z, which = z >> 2, b = z & 3;
    const short* Wm = Wb + (size_t)which * CC * CC;
    const short* Sm = (which == 0 ? xT : condT) + (size_t)b * TT * CC;
    const float* bias = which == 0 ? bq : (which == 1 ? bk : bv);
    short* Db = qkvT + ((size_t)which * NB + b) * TT * CC;
    gemm128<1>(Wm, Sm, bias, nullptr, Db);
}

__global__ __launch_bounds__(256, 2) void gemm_o_k(const short* __restrict__ Wb,
                                                   const short* __restrict__ outT,
                                                   const float* __restrict__ bo,
                                                   float* __restrict__ out) {
    int b = blockIdx.z;
    gemm128<0>(Wb + 3 * (size_t)CC * CC, outT + (size_t)b * TT * CC, bo,
               out + (size_t)b * CC * TT, nullptr);
}

// ---------------- windowed attention v5 (r5-exact, proven best) ----------------
// qkvT: bf16 [3][B][T][C]; out: bf16 [B][T][C].
// Block = 64 threads = one (b, h, 64-t tile). K and V bands (80 rows x 8
// 16B-chunks each, slot XOR swizzle c^(row&7)) staged in parallel via
// global_load_lds with clamped source rows; OOB handled by masking logits
// and p-weights in registers (zero-pad semantics). Latency-bound at the
// LDS-capped 8 waves/CU; d-split (r9), MFMA form (r6), single-band (r4),
// and setprio (r11) all measured equal-or-worse.
__global__ __launch_bounds__(64, 4) void attn5_k(const short* __restrict__ qkvT,
                                                 short* __restrict__ outT) {
    __shared__ unsigned kl[640 * 4] __attribute__((aligned(16)));
    __shared__ unsigned vl[640 * 4] __attribute__((aligned(16)));
    const int lane = threadIdx.x;
    const int t0 = blockIdx.x * 64;
    const int h = blockIdx.y, b = blockIdx.z;
    const size_t BTC = (size_t)NB * TT * CC;
    const short* qg = qkvT + (size_t)b * TT * CC + h * HD;
    const short* kg = qg + BTC;
    const short* vg = qg + 2 * BTC;

    // ---- stage K and V bands together (20 loads in flight) ----
#pragma unroll
    for (int it = 0; it < 10; ++it) {
        int idx = it * 64 + lane;          // chunk index 0..639
        int row = idx >> 3, s = idx & 7;
        int c = s ^ (row & 7);             // LDS slot s holds global chunk c
        int t = t0 - 8 + row;
        t = t < 0 ? 0 : (t > TT - 1 ? TT - 1 : t);
        const size_t off = (size_t)t * CC + c * 8;
        gld_lds16(kg + off, &kl[it * 256]);
        gld_lds16(vg + off, &vl[it * 256]);
    }

    // own Q row -> packed bf16 dwords (no conversion)
    u32x4 qv[8];
    {
        const u32x4* qr = (const u32x4*)(qg + (size_t)(t0 + lane) * CC);
#pragma unroll
        for (int c = 0; c < 8; ++c) qv[c] = qr[c];
    }

    __syncthreads();  // drains vmcnt(0)+lgkmcnt: K,V staged, Q loaded

    // ---- QK^T, 4-way split accumulators (chain depth 8) ----
    float dots[16];
#pragma unroll
    for (int w = 0; w < 16; ++w) {
        const int row = lane + w;          // LDS row (key t = t0-8+row)
        float a0 = 0.f, a1 = 0.f, a2 = 0.f, a3 = 0.f;
#pragma unroll
        for (int c = 0; c < 8; ++c) {
            u32x4 kc = *(const u32x4*)&kl[(row * 8 + (c ^ (row & 7))) * 4];
            a0 = dot2bf(qv[c][0], kc[0], a0);
            a1 = dot2bf(qv[c][1], kc[1], a1);
            a2 = dot2bf(qv[c][2], kc[2], a2);
            a3 = dot2bf(qv[c][3], kc[3], a3);
        }
        int s = t0 - 8 + row;
        // zero-pad semantics: OOB key row -> logit exactly 0
        dots[w] = ((unsigned)s < (unsigned)TT) ? ((a0 + a1) + (a2 + a3)) * 0.125f
                                               : 0.f;
    }

    // ---- softmax + pack p (bf16 pairs), masked for OOB ----
    unsigned pp[8];
    {
        float mx = dots[0];
#pragma unroll
        for (int w = 1; w < 16; ++w) mx = fmaxf(mx, dots[w]);
        float e[16], sum = 0.f;
#pragma unroll
        for (int w = 0; w < 16; ++w) {
            e[w] = __expf(dots[w] - mx);
            sum += e[w];
        }
        const float inv = 1.f / sum;
        const int sb = t0 - 8 + lane;
#pragma unroll
        for (int i = 0; i < 8; ++i) {
            float p0 = ((unsigned)(sb + 2 * i) < (unsigned)TT) ? e[2 * i] * inv : 0.f;
            float p1 = ((unsigned)(sb + 2 * i + 1) < (unsigned)TT) ? e[2 * i + 1] * inv : 0.f;
            pp[i] = (unsigned)(unsigned short)f2bf(p0) |
                    ((unsigned)(unsigned short)f2bf(p1) << 16);
        }
    }

    // ---- PV in two d-halves (32 fp32 accumulators live at a time) ----
    short* ob = outT + ((size_t)b * TT + t0 + lane) * CC + h * HD;
#pragma unroll
    for (int half = 0; half < 2; ++half) {
        float of[32];
#pragma unroll
        for (int j = 0; j < 32; ++j) of[j] = 0.f;
#pragma unroll
        for (int i = 0; i < 8; ++i) {
            const int r0 = lane + 2 * i, r1 = r0 + 1;
#pragma unroll
            for (int cl = 0; cl < 4; ++cl) {
                const int c = half * 4 + cl;
                u32x4 va = *(const u32x4*)&vl[(r0 * 8 + (c ^ (r0 & 7))) * 4];
                u32x4 vb = *(const u32x4*)&vl[(r1 * 8 + (c ^ (r1 & 7))) * 4];
#pragma unroll
                for (int d = 0; d < 4; ++d) {
                    unsigned lo = __builtin_amdgcn_perm(vb[d], va[d], 0x05040100u);
                    unsigned hi = __builtin_amdgcn_perm(vb[d], va[d], 0x07060302u);
                    of[cl * 8 + 2 * d]     = dot2bf(pp[i], lo, of[cl * 8 + 2 * d]);
                    of[cl * 8 + 2 * d + 1] = dot2bf(pp[i], hi, of[cl * 8 + 2 * d + 1]);
                }
            }
        }
#pragma unroll
        for (int cl = 0; cl < 4; ++cl) {
            s16x8 pk;
#pragma unroll
            for (int j = 0; j < 8; ++j) pk[j] = f2bf(of[cl * 8 + j]);
            *(s16x8*)&ob[half * 32 + cl * 8] = pk;
        }
    }
}

extern "C" void kernel_launch(void* const* d_in, const int* in_sizes, int n_in,
                              void* d_out, int out_size, void* d_ws, size_t ws_size,
                              hipStream_t stream) {
    const float* x    = (const float*)d_in[0];
    const float* cond = (const float*)d_in[1];
    const float* Wq   = (const float*)d_in[2];
    const float* bq   = (const float*)d_in[3];
    const float* Wk   = (const float*)d_in[4];
    const float* bk   = (const float*)d_in[5];
    const float* Wv   = (const float*)d_in[6];
    const float* bv   = (const float*)d_in[7];
    const float* Wo   = (const float*)d_in[8];
    const float* bo   = (const float*)d_in[9];

    char* ws = (char*)d_ws;
    // layout: Wb(2MB) | xT(16MB) | condT(16MB) | qkvT bf16 (48MB)
    short* Wb    = (short*)ws;
    short* xT    = (short*)(ws + (2u << 20));
    short* condT = (short*)(ws + (18u << 20));
    short* qkvT  = (short*)(ws + (34u << 20));
    short* outT  = xT;  // xT dead after Q GEMM; reuse for attention output^T

    cvt_w_k<<<4096, 256, 0, stream>>>(Wq, Wk, Wv, Wo, Wb);
    trans_k<<<dim3(TT / 64, CC / 64, 8), 256, 0, stream>>>(x, cond, xT, condT);
    gemm_qkv_k<<<dim3(TT / 128, CC / 128, 12), 256, 0, stream>>>(Wb, xT, condT, bq, bk, bv, qkvT);
    attn5_k<<<dim3(TT / 64, NH, NB), 64, 0, stream>>>(qkvT, outT);
    gemm_o_k<<<dim3(TT / 128, CC / 128, 4), 256, 0, stream>>>(Wb, outT, bo, (float*)d_out);
}